// Round 6
// baseline (5472.513 us; speedup 1.0000x reference)
//
#include <hip/hip_runtime.h>

#define N_NODES 10000
#define IN_DIM 128
#define EDGE_DIM 64
#define HID_DIM 256
#define OUT_DIM 128
#define N_EDGES 640000

// Inputs are fp32-typed (values bf16-rounded by the harness), edge_index int32.
// All-VALU diagnostic implementation: no MFMA fragment-layout assumptions,
// no workspace use, no dtype detection.

static __device__ __forceinline__ unsigned short f2bf(float f) {
    unsigned u = __builtin_bit_cast(unsigned, f);
    u = (u + 0x7fffu + ((u >> 16) & 1u)) >> 16;   // RNE; finite inputs
    return (unsigned short)u;
}
static __device__ __forceinline__ float bf2f_lo(unsigned u) {
    return __builtin_bit_cast(float, u << 16);
}
static __device__ __forceinline__ float bf2f_hi(unsigned u) {
    return __builtin_bit_cast(float, u & 0xFFFF0000u);
}

__global__ void zero_kernel(float* __restrict__ out) {
    int t = blockIdx.x * 256 + threadIdx.x;
    if (t < 320000) ((float4*)out)[t] = make_float4(0.f, 0.f, 0.f, 0.f);
}

// Block: 256 threads, handles hid-half hb = blockIdx.x & 1, grid-strided
// 16-edge groups. W1 half staged in LDS (packed bf16 pairs), W2 row-half in
// registers (o = tid & 127), m and h staged per group in LDS.
__global__ __launch_bounds__(256, 2) void gine_valu(
    const int* __restrict__ ei,
    const float* __restrict__ x,
    const float* __restrict__ ea,
    const float* __restrict__ W1,
    const float* __restrict__ b1,
    const float* __restrict__ W2,
    const float* __restrict__ b2,
    float* __restrict__ out)
{
    __shared__ unsigned        sW1u[128 * 96];   // 49,152 B: W1 half, bf16 pairs
    __shared__ unsigned        sMu[16 * 97];     //  6,208 B: m (16 edges x 192), bf16 pairs, padded
    __shared__ unsigned short  sHu[16 * 132];    //  4,224 B: h (16 edges x 128 hid), bf16
    __shared__ float           sB1[128];
    __shared__ int             sSE[16], sDE[16];

    const int tid  = threadIdx.x;
    const int hb   = blockIdx.x & 1;
    const int bseq = blockIdx.x >> 1;            // 0..511

    // ---- stage W1 half (fp32 -> packed bf16 pairs; lossless: values bf16-rounded) ----
    for (int i = tid; i < 128 * 96; i += 256) {
        int r = i / 96, c2 = i - r * 96;
        const float* wr = W1 + (hb * 128 + r) * 192 + c2 * 2;
        sW1u[r * 96 + c2] = (unsigned)f2bf(wr[0]) | ((unsigned)f2bf(wr[1]) << 16);
    }
    if (tid < 128) sB1[tid] = b1[hb * 128 + tid];

    // ---- W2 row-half in registers: o = tid & 127 ----
    const int o = tid & 127;
    unsigned w2r[64];
    #pragma unroll
    for (int j = 0; j < 64; ++j) {
        const float* wr = W2 + o * 256 + hb * 128 + j * 2;
        w2r[j] = (unsigned)f2bf(wr[0]) | ((unsigned)f2bf(wr[1]) << 16);
    }
    const float b2o = (hb == 0) ? b2[o] : 0.f;
    __syncthreads();

    for (int g = bseq; g < 40000; g += 512) {
        if (tid < 16) {
            sSE[tid] = ei[g * 16 + tid];
            sDE[tid] = ei[N_EDGES + g * 16 + tid];
        }
        __syncthreads();

        // ---- stage m = concat(x[src], edge_attr) as bf16 pairs ----
        for (int i = tid; i < 16 * 96; i += 256) {
            int ee = i / 96, c2 = i - ee * 96;
            int k = c2 * 2;
            float v0, v1;
            if (k < 128) {
                const float* xr = x + (size_t)sSE[ee] * 128 + k;
                v0 = xr[0]; v1 = xr[1];
            } else {
                const float* er = ea + (size_t)(g * 16 + ee) * 64 + (k - 128);
                v0 = er[0]; v1 = er[1];
            }
            sMu[ee * 97 + c2] = (unsigned)f2bf(v0) | ((unsigned)f2bf(v1) << 16);
        }
        __syncthreads();

        // ---- GEMM1 (VALU): h[ee][hid] = relu(b1 + sum_k m[ee][k] * W1[hid][k]) ----
        // item map: ee = tid&15 (fixed), hid = (tid>>4) + 16p
        {
            const int ee1 = tid & 15;
            const int hbase = tid >> 4;
            const unsigned* mrow = sMu + ee1 * 97;
            for (int p = 0; p < 8; ++p) {
                int hid = hbase + 16 * p;
                const unsigned* wrow = sW1u + hid * 96;
                float acc = sB1[hid];
                #pragma unroll 4
                for (int c2 = 0; c2 < 96; ++c2) {
                    unsigned wu = wrow[c2], mu = mrow[c2];
                    acc += bf2f_lo(wu) * bf2f_lo(mu) + bf2f_hi(wu) * bf2f_hi(mu);
                }
                sHu[ee1 * 132 + hid] = f2bf(fmaxf(acc, 0.f));
            }
        }
        __syncthreads();

        // ---- GEMM2 (VALU) + scatter: msg[ee][o] partial over this hid-half ----
        // item map: o = tid&127 (fixed, W2 row in regs), ee = (tid>>7)*8 + q2
        {
            const int eb = (tid >> 7) * 8;
            for (int q2 = 0; q2 < 8; ++q2) {
                int ee = eb + q2;
                const unsigned* hrow = (const unsigned*)(sHu + ee * 132); // 4B-aligned (132 even)
                float acc2 = b2o;
                #pragma unroll
                for (int j = 0; j < 64; ++j) {
                    unsigned hu = hrow[j];
                    unsigned wu = w2r[j];
                    acc2 += bf2f_lo(wu) * bf2f_lo(hu) + bf2f_hi(wu) * bf2f_hi(hu);
                }
                unsafeAtomicAdd(out + (size_t)sDE[ee] * 128 + o, acc2);
            }
        }
        __syncthreads();
    }
}

extern "C" void kernel_launch(void* const* d_in, const int* in_sizes, int n_in,
                              void* d_out, int out_size, void* d_ws, size_t ws_size,
                              hipStream_t stream) {
    const float* x  = (const float*)d_in[0];
    const int*   ei = (const int*)d_in[1];
    const float* ea = (const float*)d_in[2];
    const float* W1 = (const float*)d_in[3];
    const float* b1 = (const float*)d_in[4];
    const float* W2 = (const float*)d_in[5];
    const float* b2 = (const float*)d_in[6];
    float* out = (float*)d_out;

    zero_kernel<<<1250, 256, 0, stream>>>(out);
    gine_valu<<<1024, 256, 0, stream>>>(ei, x, ea, W1, b1, W2, b2, out);
}

// Round 7
// 2301.824 us; speedup vs baseline: 2.3775x; 2.3775x over previous
//
#include <hip/hip_runtime.h>

#define N_NODES 10000
#define IN_DIM 128
#define EDGE_DIM 64
#define HID_DIM 256
#define OUT_DIM 128
#define N_EDGES 640000

// Data contract (verified R6): fp32 buffers (values bf16-rounded), int32
// edge_index, fp32 output, atomic scatter into d_out. This round: GEMM1 via
// MFMA (bisection step), GEMM2 still VALU.

typedef __bf16 bf16x8 __attribute__((ext_vector_type(8)));
typedef float f32x4 __attribute__((ext_vector_type(4)));

static __device__ __forceinline__ unsigned short f2bf(float f) {
    unsigned u = __builtin_bit_cast(unsigned, f);
    u = (u + 0x7fffu + ((u >> 16) & 1u)) >> 16;   // RNE; finite inputs
    return (unsigned short)u;
}
static __device__ __forceinline__ float bf2f_lo(unsigned u) {
    return __builtin_bit_cast(float, u << 16);
}
static __device__ __forceinline__ float bf2f_hi(unsigned u) {
    return __builtin_bit_cast(float, u & 0xFFFF0000u);
}

__global__ void zero_kernel(float* __restrict__ out) {
    int t = blockIdx.x * 256 + threadIdx.x;
    if (t < 320000) ((float4*)out)[t] = make_float4(0.f, 0.f, 0.f, 0.f);
}

__global__ __launch_bounds__(256, 2) void gine_hybrid(
    const int* __restrict__ ei,
    const float* __restrict__ x,
    const float* __restrict__ ea,
    const float* __restrict__ W1,
    const float* __restrict__ b1,
    const float* __restrict__ W2,
    const float* __restrict__ b2,
    float* __restrict__ out)
{
    __shared__ unsigned        sW1u[128 * 97];   // 49,664 B: W1 half, bf16 pairs, +1 pad
    __shared__ unsigned        sMu[16 * 97];     //  6,208 B: m (16 edges x 192), bf16 pairs
    __shared__ unsigned short  sHu[16 * 132];    //  4,224 B: h (16 edges x 128 hid), bf16
    __shared__ float           sB1[128];
    __shared__ int             sSE[16], sDE[16];

    const int tid  = threadIdx.x;
    const int hb   = blockIdx.x & 1;
    const int bseq = blockIdx.x >> 1;            // 0..511

    // ---- stage W1 half (fp32 -> packed bf16 pairs; stride 97 uints) ----
    for (int i = tid; i < 128 * 96; i += 256) {
        int r = i / 96, c2 = i - r * 96;
        const float* wr = W1 + (hb * 128 + r) * 192 + c2 * 2;
        sW1u[r * 97 + c2] = (unsigned)f2bf(wr[0]) | ((unsigned)f2bf(wr[1]) << 16);
    }
    if (tid < 128) sB1[tid] = b1[hb * 128 + tid];

    // ---- W2 row-half in registers: o = tid & 127 ----
    const int o = tid & 127;
    unsigned w2r[64];
    #pragma unroll
    for (int j = 0; j < 64; ++j) {
        const float* wr = W2 + o * 256 + hb * 128 + j * 2;
        w2r[j] = (unsigned)f2bf(wr[0]) | ((unsigned)f2bf(wr[1]) << 16);
    }
    const float b2o = (hb == 0) ? b2[o] : 0.f;

    const int lane = tid & 63;
    const int e16  = lane & 15;
    const int q    = lane >> 4;
    const int wv   = tid >> 6;
    __syncthreads();

    for (int g = bseq; g < 40000; g += 512) {
        if (tid < 16) {
            sSE[tid] = ei[g * 16 + tid];
            sDE[tid] = ei[N_EDGES + g * 16 + tid];
        }
        __syncthreads();

        // ---- stage m = concat(x[src], edge_attr) as bf16 pairs ----
        for (int i = tid; i < 16 * 96; i += 256) {
            int ee = i / 96, c2 = i - ee * 96;
            int k = c2 * 2;
            float v0, v1;
            if (k < 128) {
                const float* xr = x + (size_t)sSE[ee] * 128 + k;
                v0 = xr[0]; v1 = xr[1];
            } else {
                const float* er = ea + (size_t)(g * 16 + ee) * 64 + (k - 128);
                v0 = er[0]; v1 = er[1];
            }
            sMu[ee * 97 + c2] = (unsigned)f2bf(v0) | ((unsigned)f2bf(v1) << 16);
        }
        __syncthreads();

        // ---- GEMM1 (MFMA): wave wv computes hid tiles mt = wv*2+{0,1} ----
        // A[m=lane&15][k=q*8+j] = W1[row=mt*16+e16][k];  B[k][n=e16] = m[e16][k]
        // D: col=e16 (edge), row=q*4+r (hid within tile)  [verified m89/m91/m120]
        {
            f32x4 acc[2];
            acc[0] = (f32x4){0.f, 0.f, 0.f, 0.f};
            acc[1] = (f32x4){0.f, 0.f, 0.f, 0.f};
            #pragma unroll
            for (int ks = 0; ks < 6; ++ks) {
                const unsigned* mp = sMu + e16 * 97 + ks * 16 + q * 4;
                int4 bi;
                bi.x = (int)mp[0]; bi.y = (int)mp[1];
                bi.z = (int)mp[2]; bi.w = (int)mp[3];
                bf16x8 bfrag = __builtin_bit_cast(bf16x8, bi);
                #pragma unroll
                for (int mtl = 0; mtl < 2; ++mtl) {
                    const unsigned* ap = sW1u + ((wv * 2 + mtl) * 16 + e16) * 97 + ks * 16 + q * 4;
                    int4 ai;
                    ai.x = (int)ap[0]; ai.y = (int)ap[1];
                    ai.z = (int)ap[2]; ai.w = (int)ap[3];
                    bf16x8 afrag = __builtin_bit_cast(bf16x8, ai);
                    acc[mtl] = __builtin_amdgcn_mfma_f32_16x16x32_bf16(afrag, bfrag, acc[mtl], 0, 0, 0);
                }
            }
            #pragma unroll
            for (int mtl = 0; mtl < 2; ++mtl) {
                const int hid = (wv * 2 + mtl) * 16 + q * 4;
                float v0 = fmaxf(acc[mtl][0] + sB1[hid + 0], 0.f);
                float v1 = fmaxf(acc[mtl][1] + sB1[hid + 1], 0.f);
                float v2 = fmaxf(acc[mtl][2] + sB1[hid + 2], 0.f);
                float v3 = fmaxf(acc[mtl][3] + sB1[hid + 3], 0.f);
                unsigned* hp = ((unsigned*)sHu) + e16 * 66 + (hid >> 1);
                hp[0] = (unsigned)f2bf(v0) | ((unsigned)f2bf(v1) << 16);
                hp[1] = (unsigned)f2bf(v2) | ((unsigned)f2bf(v3) << 16);
            }
        }
        __syncthreads();

        // ---- GEMM2 (VALU, unchanged from passing R6) + scatter ----
        {
            const int eb = (tid >> 7) * 8;
            for (int q2 = 0; q2 < 8; ++q2) {
                int ee = eb + q2;
                const unsigned* hrow = (const unsigned*)(sHu + ee * 132);
                float acc2 = b2o;
                #pragma unroll
                for (int j = 0; j < 64; ++j) {
                    unsigned hu = hrow[j];
                    unsigned wu = w2r[j];
                    acc2 += bf2f_lo(wu) * bf2f_lo(hu) + bf2f_hi(wu) * bf2f_hi(hu);
                }
                unsafeAtomicAdd(out + (size_t)sDE[ee] * 128 + o, acc2);
            }
        }
        __syncthreads();
    }
}

extern "C" void kernel_launch(void* const* d_in, const int* in_sizes, int n_in,
                              void* d_out, int out_size, void* d_ws, size_t ws_size,
                              hipStream_t stream) {
    const float* x  = (const float*)d_in[0];
    const int*   ei = (const int*)d_in[1];
    const float* ea = (const float*)d_in[2];
    const float* W1 = (const float*)d_in[3];
    const float* b1 = (const float*)d_in[4];
    const float* W2 = (const float*)d_in[5];
    const float* b2 = (const float*)d_in[6];
    float* out = (float*)d_out;

    zero_kernel<<<1250, 256, 0, stream>>>(out);
    gine_hybrid<<<1024, 256, 0, stream>>>(ei, x, ea, W1, b1, W2, b2, out);
}